// Round 1
// 441.734 us; speedup vs baseline: 1.0423x; 1.0423x over previous
//
#include <hip/hip_runtime.h>

// IterNorm (group whitening, Newton-Schulz) for x:(64,256,56,56) fp32, G=32, T=5.
// Stage 1 (k_gram): coalesced reg-staged loads -> bf16 LDS tile -> MFMA partial Gram,
//                   block-reduces 4 waves -> 512 partials (was 2048, uncoalesced).
// Stage 2 (k_ns):   256-thread per-sample reduce + sigma + Newton-Schulz.
// Stage 3 (k_apply): y = wm @ (x - mean) * weight + bias (unchanged, memory-bound).

#define HW 3136
#define NCH 256

typedef __attribute__((ext_vector_type(8)))  short bf16x8;
typedef __attribute__((ext_vector_type(16))) float f32x16;

__device__ __forceinline__ short f2bf(float f) {
    unsigned u = __builtin_bit_cast(unsigned, f);
    unsigned r = (u + 0x7FFFu + ((u >> 16) & 1u)) >> 16;   // RNE
    return (short)r;
}

// ---------------- Stage 1: partial Gram + partial channel sums ----------------
// Grid 512 = (n, cl); block 256 = 4 waves. Wave w handles hw tiles t = w, w+4, ... < 49,
// tile = 32 groups x 64 hw. Global loads: instr j reads rows 4j..4j+3, 256B contiguous
// per row (coalesced). LDS tile: bf16, 136B row stride (17 uint2) -> frag b64 reads
// hit distinct banks (2-way max = free). MFMA frag: lane holds row (lane&31),
// k = (lane>>5)*8 + j, matching A==B Gram semantics of the verified kernel.
__global__ __launch_bounds__(256) void k_gram(const float* __restrict__ x,
                                              float* __restrict__ gramPart,
                                              float* __restrict__ sxPart) {
    __shared__ uint2 stage[4][32 * 17];      // per-wave bf16 tile 32 x 64 (+8B row pad)
    __shared__ float gred[4][1024];
    __shared__ float sred[4][32][16];

    const int w    = threadIdx.x >> 6;
    const int lane = threadIdx.x & 63;
    const int n    = blockIdx.x >> 3;
    const int cl   = blockIdx.x & 7;
    const int qr   = lane >> 4;     // sub-row within a load instruction (0..3)
    const int c16  = lane & 15;     // float4 column index (0..15)
    const int frow = lane & 31;     // MFMA fragment row (group)
    const int half = lane >> 5;     // MFMA fragment k-half

    uint2* st = stage[w];

    // element addr for instr j, tile t: gbase + j*(32*HW) + t*64
    const float* gbase = x + ((size_t)(n * NCH + cl) + (size_t)qr * 8) * HW + c16 * 4;

    f32x16 acc;
    #pragma unroll
    for (int i = 0; i < 16; i++) acc[i] = 0.0f;
    float sreg[8];
    #pragma unroll
    for (int j = 0; j < 8; j++) sreg[j] = 0.0f;

    float4 v[8];
    int t = w;
    #pragma unroll
    for (int j = 0; j < 8; j++)
        v[j] = *(const float4*)(gbase + (size_t)j * (32 * HW) + t * 64);

    while (true) {
        // convert + LDS write + per-channel partial sums (channel g = 4j + qr)
        #pragma unroll
        for (int j = 0; j < 8; j++) {
            uint2 pk;
            pk.x = (unsigned)(unsigned short)f2bf(v[j].x) |
                   ((unsigned)(unsigned short)f2bf(v[j].y) << 16);
            pk.y = (unsigned)(unsigned short)f2bf(v[j].z) |
                   ((unsigned)(unsigned short)f2bf(v[j].w) << 16);
            st[(4 * j + qr) * 17 + c16] = pk;
            sreg[j] += (v[j].x + v[j].y) + (v[j].z + v[j].w);
        }
        const int tn = t + 4;
        const bool more = (tn < 49);
        if (more) {
            // prefetch next tile; vmcnt only — does not block ds_read/MFMA below
            #pragma unroll
            for (int j = 0; j < 8; j++)
                v[j] = *(const float4*)(gbase + (size_t)j * (32 * HW) + tn * 64);
        }
        // fragment reads + MFMA (same-wave ds_write->ds_read order is safe; no barrier)
        #pragma unroll
        for (int k = 0; k < 4; k++) {
            const int idx = frow * 17 + k * 4 + half * 2;
            uint2 q0 = st[idx];
            uint2 q1 = st[idx + 1];
            uint4 qq = make_uint4(q0.x, q0.y, q1.x, q1.y);
            bf16x8 f = __builtin_bit_cast(bf16x8, qq);
            acc = __builtin_amdgcn_mfma_f32_32x32x16_bf16(f, f, acc, 0, 0, 0);
        }
        if (!more) break;
        t = tn;
    }

    // block-level reduce: 4 waves -> one 32x32 partial Gram + 32 channel sums
    #pragma unroll
    for (int t16 = 0; t16 < 16; t16++) {
        const int row = (t16 & 3) + 8 * (t16 >> 2) + 4 * half;  // C/D layout (verified)
        gred[w][row * 32 + frow] = acc[t16];
    }
    #pragma unroll
    for (int j = 0; j < 8; j++) sred[w][4 * j + qr][c16] = sreg[j];
    __syncthreads();

    const int tid = threadIdx.x;
    for (int e = tid; e < 1024; e += 256) {
        float s = gred[0][e] + gred[1][e] + gred[2][e] + gred[3][e];
        gramPart[(size_t)blockIdx.x * 1024 + e] = s;
    }
    if (tid < 32) {
        float s = 0.0f;
        #pragma unroll
        for (int ww = 0; ww < 4; ww++)
            #pragma unroll
            for (int c = 0; c < 16; c++) s += sred[ww][tid][c];
        sxPart[(size_t)blockIdx.x * 32 + tid] = s;
    }
}

// ---------------- Stage 2: reduce + sigma + Newton-Schulz (256 threads/sample) ----------------
// D = X @ Y with X symmetric (X[r][k] read as X[k*32+r]). Thread -> (r = t>>3, c4 = t&7),
// computes D[r][4c4..4c4+3]. X read is 8-way broadcast (conflict-free), Y read is float4
// broadcast across 8 lanes (conflict-free).
__device__ __forceinline__ void mm256(float* __restrict__ D, const float* __restrict__ X,
                                      const float* __restrict__ Y, int r, int c4) {
    float c0 = 0.0f, c1 = 0.0f, c2 = 0.0f, c3 = 0.0f;
    #pragma unroll
    for (int k = 0; k < 32; k++) {
        const float a = X[k * 32 + r];
        const float4 y = *(const float4*)(Y + k * 32 + c4 * 4);
        c0 = fmaf(a, y.x, c0); c1 = fmaf(a, y.y, c1);
        c2 = fmaf(a, y.z, c2); c3 = fmaf(a, y.w, c3);
    }
    float4 o = { c0, c1, c2, c3 };
    *(float4*)(D + r * 32 + c4 * 4) = o;
}

__global__ __launch_bounds__(256) void k_ns(const float* __restrict__ gramPart,
                                            const float* __restrict__ sxPart,
                                            float* __restrict__ wmOut,
                                            float* __restrict__ offOut) {
    __shared__ __align__(16) float sig[1024];
    __shared__ __align__(16) float P[1024];
    __shared__ __align__(16) float A[1024];
    __shared__ __align__(16) float B[1024];
    __shared__ float meanS[32];
    __shared__ float tiS;

    const int n = blockIdx.x;
    const int t = threadIdx.x;

    if (t < 32) {
        float s = 0.0f;
        #pragma unroll
        for (int cl = 0; cl < 8; cl++) s += sxPart[((size_t)n * 8 + cl) * 32 + t];
        meanS[t] = s * (1.0f / 25088.0f);
    }
    __syncthreads();

    for (int e = t; e < 1024; e += 256) {
        float s = 0.0f;
        #pragma unroll
        for (int p = 0; p < 8; p++) s += gramPart[((size_t)n * 8 + p) * 1024 + e];
        sig[e] = s * (1.0f / 25088.0f) - meanS[e >> 5] * meanS[e & 31];
    }
    __syncthreads();

    if (t < 64) {
        float d = (t < 32) ? sig[t * 33] : 0.0f;
        #pragma unroll
        for (int o = 16; o > 0; o >>= 1) d += __shfl_down(d, o);
        if (t == 0) tiS = 1.0f / d;
    }
    __syncthreads();
    const float ti = tiS;
    for (int e = t; e < 1024; e += 256) {
        sig[e] *= ti;
        P[e] = ((e >> 5) == (e & 31)) ? 1.0f : 0.0f;
    }
    __syncthreads();

    const int r  = t >> 3;
    const int c4 = t & 7;
    for (int it = 0; it < 5; it++) {
        mm256(A, P, P, r, c4);   __syncthreads();   // A = P^2
        mm256(B, A, P, r, c4);   __syncthreads();   // B = P^3
        mm256(A, B, sig, r, c4); __syncthreads();   // A = P^3 @ sigma_n
        for (int e = t; e < 1024; e += 256) P[e] = 1.5f * P[e] - 0.5f * A[e];
        __syncthreads();
    }

    const float sti = sqrtf(ti);
    for (int e = t; e < 1024; e += 256) wmOut[(size_t)n * 1024 + e] = P[e] * sti;
    if (t < 32) {
        float s = 0.0f;
        #pragma unroll
        for (int h = 0; h < 32; h++) s += P[t * 32 + h] * meanS[h];
        offOut[n * 32 + t] = s * sti;   // off[g] = sum_h wm[g][h]*mean[h]
    }
}

// ---------------- Stage 3: apply whitening (unchanged) ----------------
__global__ __launch_bounds__(256) void k_apply(const float* __restrict__ x,
                                               const float* __restrict__ wm,
                                               const float* __restrict__ off,
                                               const float* __restrict__ weight,
                                               const float* __restrict__ bias,
                                               float* __restrict__ out) {
    int n  = blockIdx.x / 98;            // uniform per block (25088/256 = 98 exact)
    int rb = blockIdx.x % 98;
    int idx = rb * 256 + threadIdx.x;    // 0..25087
    int cl = idx / HW;
    int hw = idx % HW;

    const float* xb = x + (size_t)n * NCH * HW + cl * HW + hw;
    float xv[32];
    #pragma unroll
    for (int h = 0; h < 32; h++) xv[h] = xb[(size_t)h * 8 * HW];

    const float* wmn  = wm + (size_t)n * 1024;   // uniform pointer -> scalar loads
    const float* offn = off + n * 32;
    float* ob = out + (size_t)n * NCH * HW + cl * HW + hw;

    for (int g = 0; g < 32; g++) {
        float s = -offn[g];
        #pragma unroll
        for (int h = 0; h < 32; h++) s = fmaf(wmn[g * 32 + h], xv[h], s);
        int c = g * 8 + cl;
        ob[(size_t)g * 8 * HW] = s * weight[c] + bias[c];
    }
}

extern "C" void kernel_launch(void* const* d_in, const int* in_sizes, int n_in,
                              void* d_out, int out_size, void* d_ws, size_t ws_size,
                              hipStream_t stream) {
    const float* x      = (const float*)d_in[0];
    const float* weight = (const float*)d_in[1];
    const float* bias   = (const float*)d_in[2];
    float* out = (float*)d_out;

    // ws layout (floats): gramPart 512*1024 | sxPart 512*32 | wm 64*1024 | off 64*32 (~2.4 MB)
    float* ws       = (float*)d_ws;
    float* gramPart = ws;
    float* sxPart   = gramPart + (size_t)512 * 1024;
    float* wmOut    = sxPart + (size_t)512 * 32;
    float* offOut   = wmOut + (size_t)64 * 1024;

    hipLaunchKernelGGL(k_gram,  dim3(512),  dim3(256), 0, stream, x, gramPart, sxPart);
    hipLaunchKernelGGL(k_ns,    dim3(64),   dim3(256), 0, stream, gramPart, sxPart, wmOut, offOut);
    hipLaunchKernelGGL(k_apply, dim3(6272), dim3(256), 0, stream, x, wmOut, offOut, weight, bias, out);
}

// Round 2
// 404.742 us; speedup vs baseline: 1.1376x; 1.0914x over previous
//
#include <hip/hip_runtime.h>

// IterNorm (group whitening, Newton-Schulz) for x:(64,256,56,56) fp32, G=32, T=5.
// Stage 1 (k_gram): coalesced reg-staged loads -> bf16 LDS tile -> MFMA partial Gram.
// Stage 2 (k_ns):   256-thread per-sample reduce + sigma + Newton-Schulz.
// Stage 3 (k_apply): float4-vectorized whitening apply; nontemporal out-stores keep
//                    x L3-resident (x was fully cached by k_gram's pass).

#define HW 3136
#define NCH 256

typedef __attribute__((ext_vector_type(8)))  short bf16x8;
typedef __attribute__((ext_vector_type(16))) float f32x16;
typedef __attribute__((ext_vector_type(4)))  float f32x4;

__device__ __forceinline__ short f2bf(float f) {
    unsigned u = __builtin_bit_cast(unsigned, f);
    unsigned r = (u + 0x7FFFu + ((u >> 16) & 1u)) >> 16;   // RNE
    return (short)r;
}

// ---------------- Stage 1: partial Gram + partial channel sums ----------------
// Grid 512 = (n, cl); block 256 = 4 waves. Wave w handles hw tiles t = w, w+4, ... < 49,
// tile = 32 groups x 64 hw. Global loads: instr j reads rows 4j..4j+3, 256B contiguous
// per row (coalesced). LDS tile: bf16, 136B row stride (17 uint2) -> frag b64 reads
// hit distinct banks. MFMA frag: lane holds row (lane&31), k = (lane>>5)*8 + j.
__global__ __launch_bounds__(256) void k_gram(const float* __restrict__ x,
                                              float* __restrict__ gramPart,
                                              float* __restrict__ sxPart) {
    __shared__ uint2 stage[4][32 * 17];      // per-wave bf16 tile 32 x 64 (+8B row pad)
    __shared__ float gred[4][1024];
    __shared__ float sred[4][32][16];

    const int w    = threadIdx.x >> 6;
    const int lane = threadIdx.x & 63;
    const int n    = blockIdx.x >> 3;
    const int cl   = blockIdx.x & 7;
    const int qr   = lane >> 4;     // sub-row within a load instruction (0..3)
    const int c16  = lane & 15;     // float4 column index (0..15)
    const int frow = lane & 31;     // MFMA fragment row (group)
    const int half = lane >> 5;     // MFMA fragment k-half

    uint2* st = stage[w];

    // element addr for instr j, tile t: gbase + j*(32*HW) + t*64
    const float* gbase = x + ((size_t)(n * NCH + cl) + (size_t)qr * 8) * HW + c16 * 4;

    f32x16 acc;
    #pragma unroll
    for (int i = 0; i < 16; i++) acc[i] = 0.0f;
    float sreg[8];
    #pragma unroll
    for (int j = 0; j < 8; j++) sreg[j] = 0.0f;

    float4 v[8];
    int t = w;
    #pragma unroll
    for (int j = 0; j < 8; j++)
        v[j] = *(const float4*)(gbase + (size_t)j * (32 * HW) + t * 64);

    while (true) {
        // convert + LDS write + per-channel partial sums (channel g = 4j + qr)
        #pragma unroll
        for (int j = 0; j < 8; j++) {
            uint2 pk;
            pk.x = (unsigned)(unsigned short)f2bf(v[j].x) |
                   ((unsigned)(unsigned short)f2bf(v[j].y) << 16);
            pk.y = (unsigned)(unsigned short)f2bf(v[j].z) |
                   ((unsigned)(unsigned short)f2bf(v[j].w) << 16);
            st[(4 * j + qr) * 17 + c16] = pk;
            sreg[j] += (v[j].x + v[j].y) + (v[j].z + v[j].w);
        }
        const int tn = t + 4;
        const bool more = (tn < 49);
        if (more) {
            #pragma unroll
            for (int j = 0; j < 8; j++)
                v[j] = *(const float4*)(gbase + (size_t)j * (32 * HW) + tn * 64);
        }
        // fragment reads + MFMA (same-wave ds_write->ds_read order is safe; no barrier)
        #pragma unroll
        for (int k = 0; k < 4; k++) {
            const int idx = frow * 17 + k * 4 + half * 2;
            uint2 q0 = st[idx];
            uint2 q1 = st[idx + 1];
            uint4 qq = make_uint4(q0.x, q0.y, q1.x, q1.y);
            bf16x8 f = __builtin_bit_cast(bf16x8, qq);
            acc = __builtin_amdgcn_mfma_f32_32x32x16_bf16(f, f, acc, 0, 0, 0);
        }
        if (!more) break;
        t = tn;
    }

    // block-level reduce: 4 waves -> one 32x32 partial Gram + 32 channel sums
    #pragma unroll
    for (int t16 = 0; t16 < 16; t16++) {
        const int row = (t16 & 3) + 8 * (t16 >> 2) + 4 * half;  // C/D layout (verified)
        gred[w][row * 32 + frow] = acc[t16];
    }
    #pragma unroll
    for (int j = 0; j < 8; j++) sred[w][4 * j + qr][c16] = sreg[j];
    __syncthreads();

    const int tid = threadIdx.x;
    for (int e = tid; e < 1024; e += 256) {
        float s = gred[0][e] + gred[1][e] + gred[2][e] + gred[3][e];
        gramPart[(size_t)blockIdx.x * 1024 + e] = s;
    }
    if (tid < 32) {
        float s = 0.0f;
        #pragma unroll
        for (int ww = 0; ww < 4; ww++)
            #pragma unroll
            for (int c = 0; c < 16; c++) s += sred[ww][tid][c];
        sxPart[(size_t)blockIdx.x * 32 + tid] = s;
    }
}

// ---------------- Stage 2: reduce + sigma + Newton-Schulz (256 threads/sample) ----------------
__device__ __forceinline__ void mm256(float* __restrict__ D, const float* __restrict__ X,
                                      const float* __restrict__ Y, int r, int c4) {
    float c0 = 0.0f, c1 = 0.0f, c2 = 0.0f, c3 = 0.0f;
    #pragma unroll
    for (int k = 0; k < 32; k++) {
        const float a = X[k * 32 + r];
        const float4 y = *(const float4*)(Y + k * 32 + c4 * 4);
        c0 = fmaf(a, y.x, c0); c1 = fmaf(a, y.y, c1);
        c2 = fmaf(a, y.z, c2); c3 = fmaf(a, y.w, c3);
    }
    float4 o = { c0, c1, c2, c3 };
    *(float4*)(D + r * 32 + c4 * 4) = o;
}

__global__ __launch_bounds__(256) void k_ns(const float* __restrict__ gramPart,
                                            const float* __restrict__ sxPart,
                                            float* __restrict__ wmOut,
                                            float* __restrict__ offOut) {
    __shared__ __align__(16) float sig[1024];
    __shared__ __align__(16) float P[1024];
    __shared__ __align__(16) float A[1024];
    __shared__ __align__(16) float B[1024];
    __shared__ float meanS[32];
    __shared__ float tiS;

    const int n = blockIdx.x;
    const int t = threadIdx.x;

    if (t < 32) {
        float s = 0.0f;
        #pragma unroll
        for (int cl = 0; cl < 8; cl++) s += sxPart[((size_t)n * 8 + cl) * 32 + t];
        meanS[t] = s * (1.0f / 25088.0f);
    }
    __syncthreads();

    for (int e = t; e < 1024; e += 256) {
        float s = 0.0f;
        #pragma unroll
        for (int p = 0; p < 8; p++) s += gramPart[((size_t)n * 8 + p) * 1024 + e];
        sig[e] = s * (1.0f / 25088.0f) - meanS[e >> 5] * meanS[e & 31];
    }
    __syncthreads();

    if (t < 64) {
        float d = (t < 32) ? sig[t * 33] : 0.0f;
        #pragma unroll
        for (int o = 16; o > 0; o >>= 1) d += __shfl_down(d, o);
        if (t == 0) tiS = 1.0f / d;
    }
    __syncthreads();
    const float ti = tiS;
    for (int e = t; e < 1024; e += 256) {
        sig[e] *= ti;
        P[e] = ((e >> 5) == (e & 31)) ? 1.0f : 0.0f;
    }
    __syncthreads();

    const int r  = t >> 3;
    const int c4 = t & 7;
    for (int it = 0; it < 5; it++) {
        mm256(A, P, P, r, c4);   __syncthreads();   // A = P^2
        mm256(B, A, P, r, c4);   __syncthreads();   // B = P^3
        mm256(A, B, sig, r, c4); __syncthreads();   // A = P^3 @ sigma_n
        for (int e = t; e < 1024; e += 256) P[e] = 1.5f * P[e] - 0.5f * A[e];
        __syncthreads();
    }

    const float sti = sqrtf(ti);
    for (int e = t; e < 1024; e += 256) wmOut[(size_t)n * 1024 + e] = P[e] * sti;
    if (t < 32) {
        float s = 0.0f;
        #pragma unroll
        for (int h = 0; h < 32; h++) s += P[t * 32 + h] * meanS[h];
        offOut[n * 32 + t] = s * sti;   // off[g] = sum_h wm[g][h]*mean[h]
    }
}

// ---------------- Stage 3: apply whitening (float4 + nontemporal stores) ----------------
// Thread -> (n, cl, hw4): 4 consecutive hw per thread. Grid 64*25 blocks; n uniform per
// block -> wm/off stay scalar (s_load). Out-stores are nontemporal so x stays L3-resident.
__global__ __launch_bounds__(256) void k_apply(const float* __restrict__ x,
                                               const float* __restrict__ wm,
                                               const float* __restrict__ off,
                                               const float* __restrict__ weight,
                                               const float* __restrict__ bias,
                                               float* __restrict__ out) {
    const int n   = blockIdx.x / 25;          // uniform per block
    const int rb  = blockIdx.x % 25;
    const int idx = rb * 256 + threadIdx.x;   // 0..6399, active < 6272 (= 8 cl * 784)
    if (idx >= 6272) return;
    const int cl  = idx / 784;
    const int hw  = (idx % 784) * 4;

    const float* xb = x + (size_t)n * NCH * HW + cl * HW + hw;
    f32x4 xv[32];
    #pragma unroll
    for (int h = 0; h < 32; h++)
        xv[h] = *(const f32x4*)(xb + (size_t)h * 8 * HW);

    const float* wmn  = wm + (size_t)n * 1024;   // uniform pointer -> scalar loads
    const float* offn = off + n * 32;
    float* ob = out + (size_t)n * NCH * HW + cl * HW + hw;

    for (int g = 0; g < 32; g++) {
        const float o = offn[g];
        f32x4 s = { -o, -o, -o, -o };
        #pragma unroll
        for (int h = 0; h < 32; h++) {
            const float a = wmn[g * 32 + h];
            s.x = fmaf(a, xv[h].x, s.x);
            s.y = fmaf(a, xv[h].y, s.y);
            s.z = fmaf(a, xv[h].z, s.z);
            s.w = fmaf(a, xv[h].w, s.w);
        }
        const int c = g * 8 + cl;
        const float wv = weight[c];
        const float bv = bias[c];
        f32x4 o4;
        o4.x = fmaf(s.x, wv, bv);
        o4.y = fmaf(s.y, wv, bv);
        o4.z = fmaf(s.z, wv, bv);
        o4.w = fmaf(s.w, wv, bv);
        __builtin_nontemporal_store(o4, (f32x4*)(ob + (size_t)g * 8 * HW));
    }
}

extern "C" void kernel_launch(void* const* d_in, const int* in_sizes, int n_in,
                              void* d_out, int out_size, void* d_ws, size_t ws_size,
                              hipStream_t stream) {
    const float* x      = (const float*)d_in[0];
    const float* weight = (const float*)d_in[1];
    const float* bias   = (const float*)d_in[2];
    float* out = (float*)d_out;

    // ws layout (floats): gramPart 512*1024 | sxPart 512*32 | wm 64*1024 | off 64*32 (~2.4 MB)
    float* ws       = (float*)d_ws;
    float* gramPart = ws;
    float* sxPart   = gramPart + (size_t)512 * 1024;
    float* wmOut    = sxPart + (size_t)512 * 32;
    float* offOut   = wmOut + (size_t)64 * 1024;

    hipLaunchKernelGGL(k_gram,  dim3(512),  dim3(256), 0, stream, x, gramPart, sxPart);
    hipLaunchKernelGGL(k_ns,    dim3(64),   dim3(256), 0, stream, gramPart, sxPart, wmOut, offOut);
    hipLaunchKernelGGL(k_apply, dim3(1600), dim3(256), 0, stream, x, wmOut, offOut, weight, bias, out);
}

// Round 5
// 397.349 us; speedup vs baseline: 1.1588x; 1.0186x over previous
//
#include <hip/hip_runtime.h>

// IterNorm (group whitening, Newton-Schulz) for x:(64,256,56,56) fp32, G=32, T=5.
// Stage 1 (k_gram): coalesced reg-staged loads -> bf16 LDS tile -> MFMA partial Gram.
// Stage 2 (k_ns):   256-thread per-sample reduce + sigma + Newton-Schulz; emits wm^T.
// Stage 3 (k_apply): accumulator-streaming whitening apply (s[32] resident, x streamed
//                    as float2) -> ~90 VGPR, 2x occupancy vs xv[32] version; nt stores
//                    keep x L3-resident.
// (Round 5 = third submission of the round-3 source: rounds 3 and 4 both died with
//  "MI355X container failed twice" — an acquire/infra failure, no kernel verdict.
//  All constructs are proven on this toolchain by the round-2 pass; indexing audited
//  in-bounds. If this fails identically again, next round bisects with the round-2
//  known-good kernel.)

#define HW 3136
#define NCH 256

typedef __attribute__((ext_vector_type(8)))  short bf16x8;
typedef __attribute__((ext_vector_type(16))) float f32x16;
typedef __attribute__((ext_vector_type(2)))  float f32x2;

__device__ __forceinline__ short f2bf(float f) {
    unsigned u = __builtin_bit_cast(unsigned, f);
    unsigned r = (u + 0x7FFFu + ((u >> 16) & 1u)) >> 16;   // RNE
    return (short)r;
}

// ---------------- Stage 1: partial Gram + partial channel sums ----------------
// Grid 512 = (n, cl); block 256 = 4 waves. Wave w handles hw tiles t = w, w+4, ... < 49,
// tile = 32 groups x 64 hw. Global loads: instr j reads rows 4j..4j+3, 256B contiguous
// per row (coalesced). LDS tile: bf16, 136B row stride (17 uint2) -> frag b64 reads
// hit distinct banks. MFMA frag: lane holds row (lane&31), k = (lane>>5)*8 + j.
__global__ __launch_bounds__(256) void k_gram(const float* __restrict__ x,
                                              float* __restrict__ gramPart,
                                              float* __restrict__ sxPart) {
    __shared__ uint2 stage[4][32 * 17];      // per-wave bf16 tile 32 x 64 (+8B row pad)
    __shared__ float gred[4][1024];
    __shared__ float sred[4][32][16];

    const int w    = threadIdx.x >> 6;
    const int lane = threadIdx.x & 63;
    const int n    = blockIdx.x >> 3;
    const int cl   = blockIdx.x & 7;
    const int qr   = lane >> 4;     // sub-row within a load instruction (0..3)
    const int c16  = lane & 15;     // float4 column index (0..15)
    const int frow = lane & 31;     // MFMA fragment row (group)
    const int half = lane >> 5;     // MFMA fragment k-half

    uint2* st = stage[w];

    // element addr for instr j, tile t: gbase + j*(32*HW) + t*64
    const float* gbase = x + ((size_t)(n * NCH + cl) + (size_t)qr * 8) * HW + c16 * 4;

    f32x16 acc;
    #pragma unroll
    for (int i = 0; i < 16; i++) acc[i] = 0.0f;
    float sreg[8];
    #pragma unroll
    for (int j = 0; j < 8; j++) sreg[j] = 0.0f;

    float4 v[8];
    int t = w;
    #pragma unroll
    for (int j = 0; j < 8; j++)
        v[j] = *(const float4*)(gbase + (size_t)j * (32 * HW) + t * 64);

    while (true) {
        // convert + LDS write + per-channel partial sums (channel g = 4j + qr)
        #pragma unroll
        for (int j = 0; j < 8; j++) {
            uint2 pk;
            pk.x = (unsigned)(unsigned short)f2bf(v[j].x) |
                   ((unsigned)(unsigned short)f2bf(v[j].y) << 16);
            pk.y = (unsigned)(unsigned short)f2bf(v[j].z) |
                   ((unsigned)(unsigned short)f2bf(v[j].w) << 16);
            st[(4 * j + qr) * 17 + c16] = pk;
            sreg[j] += (v[j].x + v[j].y) + (v[j].z + v[j].w);
        }
        const int tn = t + 4;
        const bool more = (tn < 49);
        if (more) {
            #pragma unroll
            for (int j = 0; j < 8; j++)
                v[j] = *(const float4*)(gbase + (size_t)j * (32 * HW) + tn * 64);
        }
        // fragment reads + MFMA (same-wave ds_write->ds_read order is safe; no barrier)
        #pragma unroll
        for (int k = 0; k < 4; k++) {
            const int idx = frow * 17 + k * 4 + half * 2;
            uint2 q0 = st[idx];
            uint2 q1 = st[idx + 1];
            uint4 qq = make_uint4(q0.x, q0.y, q1.x, q1.y);
            bf16x8 f = __builtin_bit_cast(bf16x8, qq);
            acc = __builtin_amdgcn_mfma_f32_32x32x16_bf16(f, f, acc, 0, 0, 0);
        }
        if (!more) break;
        t = tn;
    }

    // block-level reduce: 4 waves -> one 32x32 partial Gram + 32 channel sums
    #pragma unroll
    for (int t16 = 0; t16 < 16; t16++) {
        const int row = (t16 & 3) + 8 * (t16 >> 2) + 4 * half;  // C/D layout (verified)
        gred[w][row * 32 + frow] = acc[t16];
    }
    #pragma unroll
    for (int j = 0; j < 8; j++) sred[w][4 * j + qr][c16] = sreg[j];
    __syncthreads();

    const int tid = threadIdx.x;
    for (int e = tid; e < 1024; e += 256) {
        float s = gred[0][e] + gred[1][e] + gred[2][e] + gred[3][e];
        gramPart[(size_t)blockIdx.x * 1024 + e] = s;
    }
    if (tid < 32) {
        float s = 0.0f;
        #pragma unroll
        for (int ww = 0; ww < 4; ww++)
            #pragma unroll
            for (int c = 0; c < 16; c++) s += sred[ww][tid][c];
        sxPart[(size_t)blockIdx.x * 32 + tid] = s;
    }
}

// ---------------- Stage 2: reduce + sigma + Newton-Schulz (256 threads/sample) ----------------
__device__ __forceinline__ void mm256(float* __restrict__ D, const float* __restrict__ X,
                                      const float* __restrict__ Y, int r, int c4) {
    float c0 = 0.0f, c1 = 0.0f, c2 = 0.0f, c3 = 0.0f;
    #pragma unroll
    for (int k = 0; k < 32; k++) {
        const float a = X[k * 32 + r];
        const float4 y = *(const float4*)(Y + k * 32 + c4 * 4);
        c0 = fmaf(a, y.x, c0); c1 = fmaf(a, y.y, c1);
        c2 = fmaf(a, y.z, c2); c3 = fmaf(a, y.w, c3);
    }
    float4 o = { c0, c1, c2, c3 };
    *(float4*)(D + r * 32 + c4 * 4) = o;
}

__global__ __launch_bounds__(256) void k_ns(const float* __restrict__ gramPart,
                                            const float* __restrict__ sxPart,
                                            float* __restrict__ wmT,     // (n, h, g): transposed
                                            float* __restrict__ offOut) {
    __shared__ __align__(16) float sig[1024];
    __shared__ __align__(16) float P[1024];
    __shared__ __align__(16) float A[1024];
    __shared__ __align__(16) float B[1024];
    __shared__ float meanS[32];
    __shared__ float tiS;

    const int n = blockIdx.x;
    const int t = threadIdx.x;

    if (t < 32) {
        float s = 0.0f;
        #pragma unroll
        for (int cl = 0; cl < 8; cl++) s += sxPart[((size_t)n * 8 + cl) * 32 + t];
        meanS[t] = s * (1.0f / 25088.0f);
    }
    __syncthreads();

    for (int e = t; e < 1024; e += 256) {
        float s = 0.0f;
        #pragma unroll
        for (int p = 0; p < 8; p++) s += gramPart[((size_t)n * 8 + p) * 1024 + e];
        sig[e] = s * (1.0f / 25088.0f) - meanS[e >> 5] * meanS[e & 31];
    }
    __syncthreads();

    if (t < 64) {
        float d = (t < 32) ? sig[t * 33] : 0.0f;
        #pragma unroll
        for (int o = 16; o > 0; o >>= 1) d += __shfl_down(d, o);
        if (t == 0) tiS = 1.0f / d;
    }
    __syncthreads();
    const float ti = tiS;
    for (int e = t; e < 1024; e += 256) {
        sig[e] *= ti;
        P[e] = ((e >> 5) == (e & 31)) ? 1.0f : 0.0f;
    }
    __syncthreads();

    const int r  = t >> 3;
    const int c4 = t & 7;
    for (int it = 0; it < 5; it++) {
        mm256(A, P, P, r, c4);   __syncthreads();   // A = P^2
        mm256(B, A, P, r, c4);   __syncthreads();   // B = P^3
        mm256(A, B, sig, r, c4); __syncthreads();   // A = P^3 @ sigma_n
        for (int e = t; e < 1024; e += 256) P[e] = 1.5f * P[e] - 0.5f * A[e];
        __syncthreads();
    }

    const float sti = sqrtf(ti);
    // emit wm^T: wmT[n, h*32+g] = P[g*32+h] * sti   (apply reads h-rows contiguously)
    for (int e = t; e < 1024; e += 256)
        wmT[(size_t)n * 1024 + e] = P[(e & 31) * 32 + (e >> 5)] * sti;
    if (t < 32) {
        float s = 0.0f;
        #pragma unroll
        for (int h = 0; h < 32; h++) s += P[t * 32 + h] * meanS[h];
        offOut[n * 32 + t] = s * sti;   // off[g] = sum_h wm[g][h]*mean[h]
    }
}

// ---------------- Stage 3: apply whitening (accumulator-streaming, float2) ----------------
// Thread -> (n, cl, hw2): 2 consecutive hw. s[32] f32x2 accumulators stay resident
// (~90 VGPR -> 4 waves/SIMD); x streamed one group-channel at a time (8B/lane coalesced).
// wm read via wmT: per-h row of 32 contiguous uniform floats -> scalar loads.
// Nontemporal out-stores keep x L3-resident.
__global__ __launch_bounds__(256) void k_apply(const float* __restrict__ x,
                                               const float* __restrict__ wmT,
                                               const float* __restrict__ off,
                                               const float* __restrict__ weight,
                                               const float* __restrict__ bias,
                                               float* __restrict__ out) {
    const int n   = blockIdx.x / 49;           // uniform per block (49*256 = 8*1568 exact)
    const int rb  = blockIdx.x % 49;
    const int idx = rb * 256 + threadIdx.x;    // 0..12543
    const int cl  = idx / 1568;
    const int hw  = (idx % 1568) * 2;

    const float* xb = x   + (size_t)n * NCH * HW + cl * HW + hw;
    const float* wt = wmT + (size_t)n * 1024;  // uniform -> scalar loads

    f32x2 s[32];
    #pragma unroll
    for (int g = 0; g < 32; g++) { s[g][0] = 0.0f; s[g][1] = 0.0f; }

    #pragma unroll 4
    for (int h = 0; h < 32; h++) {
        const f32x2 xv = *(const f32x2*)(xb + (size_t)h * 8 * HW);
        const float* a = wt + h * 32;
        #pragma unroll
        for (int g = 0; g < 32; g++) {
            s[g][0] = fmaf(a[g], xv[0], s[g][0]);
            s[g][1] = fmaf(a[g], xv[1], s[g][1]);
        }
    }

    const float* offn = off + n * 32;          // uniform -> scalar loads
    float* ob = out + (size_t)n * NCH * HW + cl * HW + hw;
    #pragma unroll
    for (int g = 0; g < 32; g++) {
        const int c = g * 8 + cl;
        const float wv = weight[c];
        const float bv = bias[c];
        const float o  = offn[g];
        f32x2 r;
        r[0] = fmaf(s[g][0] - o, wv, bv);
        r[1] = fmaf(s[g][1] - o, wv, bv);
        __builtin_nontemporal_store(r, (f32x2*)(ob + (size_t)g * 8 * HW));
    }
}

extern "C" void kernel_launch(void* const* d_in, const int* in_sizes, int n_in,
                              void* d_out, int out_size, void* d_ws, size_t ws_size,
                              hipStream_t stream) {
    const float* x      = (const float*)d_in[0];
    const float* weight = (const float*)d_in[1];
    const float* bias   = (const float*)d_in[2];
    float* out = (float*)d_out;

    // ws layout (floats): gramPart 512*1024 | sxPart 512*32 | wmT 64*1024 | off 64*32 (~2.4 MB)
    float* ws       = (float*)d_ws;
    float* gramPart = ws;
    float* sxPart   = gramPart + (size_t)512 * 1024;
    float* wmT      = sxPart + (size_t)512 * 32;
    float* offOut   = wmT + (size_t)64 * 1024;

    hipLaunchKernelGGL(k_gram,  dim3(512),  dim3(256), 0, stream, x, gramPart, sxPart);
    hipLaunchKernelGGL(k_ns,    dim3(64),   dim3(256), 0, stream, gramPart, sxPart, wmT, offOut);
    hipLaunchKernelGGL(k_apply, dim3(3136), dim3(256), 0, stream, x, wmT, offOut, weight, bias, out);
}